// Round 10
// baseline (223.068 us; speedup 1.0000x reference)
//
#include <hip/hip_runtime.h>
#include <hip/hip_bf16.h>
#include <cstdint>

#define BQ 8
#define NQ 2048
#define FQ 128

typedef __attribute__((ext_vector_type(8))) short short8;
typedef __attribute__((ext_vector_type(4))) float f32x4;
typedef __attribute__((ext_vector_type(8))) unsigned short us8;
typedef __attribute__((ext_vector_type(2))) unsigned int u32x2;

__device__ __forceinline__ unsigned short f2bf(float f) {
    union { float f; unsigned int u; } c; c.f = f;
    unsigned int u = c.u;
    u = (u + 0x7FFFu + ((u >> 16) & 1u)) >> 16;   // RNE
    return (unsigned short)u;
}

__device__ __forceinline__ unsigned int cvtpk(float lo, float hi) {
    unsigned int r;
    asm("v_cvt_pk_bf16_f32 %0, %1, %2" : "=v"(r) : "v"(lo), "v"(hi));
    return r;
}

// Layouts (per batch):
//   xnF : [n/16][k/8][n%16][k%8]  addr = (n>>4)*2048 + (k>>3)*128 + (n&15)*8 + (k&7)
//   hsF : [m/8][f][m%8]           addr = (m>>3)*1024 + f*8 + (m&7)

// ---- Kernel 1: row L2-normalize h -> xnF (16 rows/block) ----
__global__ __launch_bounds__(256) void k_rownorm(const float* __restrict__ h,
                                                 unsigned short* __restrict__ xnF) {
    int t = threadIdx.x;
    int rl = t >> 4, j = t & 15;
    size_t row = (size_t)blockIdx.x * 16 + rl;
    const float* hr = h + row * FQ + j * 8;
    float v[8];
    #pragma unroll
    for (int e = 0; e < 8; ++e) v[e] = hr[e];
    float s = 0.f;
    #pragma unroll
    for (int e = 0; e < 8; ++e) s += v[e] * v[e];
    s += __shfl_xor(s, 1, 64);
    s += __shfl_xor(s, 2, 64);
    s += __shfl_xor(s, 4, 64);
    s += __shfl_xor(s, 8, 64);
    float inv = 1.0f / fmaxf(sqrtf(s), 1e-8f);
    us8 u;
    #pragma unroll
    for (int e = 0; e < 8; ++e) u[e] = f2bf(v[e] * inv);
    *(us8*)(xnF + (size_t)blockIdx.x * 2048 + j * 128 + rl * 8) = u;
}

// ---- Kernel 2: d[n] = sum_m threshold(S[n][m]) (no S store).
//      Block = 32 rows; 4 waves = 2 row-groups x 2 col-halves. ----
__global__ __launch_bounds__(256) void k_dsum(const unsigned short* __restrict__ xnF,
                                              float* __restrict__ d, float t) {
    int bid = blockIdx.x;
    int lb = (bid & 7) * 64 + (bid >> 3);        // XCD swizzle: batch-per-XCD
    int bb = lb >> 6;
    int blk = lb & 63;
    int row_base = blk * 32;
    int wid = threadIdx.x >> 6, lane = threadIdx.x & 63;
    int g = lane >> 4, c = lane & 15;
    int ig = wid >> 1, ch = wid & 1;

    const unsigned short* xb = xnF + (size_t)bb * NQ * FQ;
    short8 a[4];
    #pragma unroll
    for (int ks = 0; ks < 4; ++ks)
        a[ks] = *(const short8*)(xb + (size_t)(blk * 2 + ig) * 2048 + (ks * 4 + g) * 128 + c * 8);

    float dl[4] = {0.f, 0.f, 0.f, 0.f};
    for (int ct = 0; ct < 64; ++ct) {
        int j16 = ch * 64 + ct;
        f32x4 acc = (f32x4){0.f, 0.f, 0.f, 0.f};
        #pragma unroll
        for (int ks = 0; ks < 4; ++ks) {
            short8 b = *(const short8*)(xb + (size_t)j16 * 2048 + (ks * 4 + g) * 128 + c * 8);
            acc = __builtin_amdgcn_mfma_f32_16x16x32_bf16(a[ks], b, acc, 0, 0, 0);
        }
        #pragma unroll
        for (int r = 0; r < 4; ++r) {
            float v = acc[r];
            dl[r] += (v > t) ? v : 0.0f;        // strict threshold
        }
    }
    #pragma unroll
    for (int r = 0; r < 4; ++r) {
        float s = dl[r];
        s += __shfl_xor(s, 1, 64);
        s += __shfl_xor(s, 2, 64);
        s += __shfl_xor(s, 4, 64);
        s += __shfl_xor(s, 8, 64);
        dl[r] = s;
    }
    __shared__ float dsm[4][16];
    if (c == 0) {
        #pragma unroll
        for (int r = 0; r < 4; ++r) dsm[wid][g * 4 + r] = dl[r];
    }
    __syncthreads();
    int tid = threadIdx.x;
    if (tid < 32)
        d[(size_t)bb * NQ + row_base + tid] = dsm[(tid >> 4) * 2][tid & 15]
                                            + dsm[(tid >> 4) * 2 + 1][tid & 15];
}

// ---- Kernel 3: isq = 1/sqrt(d); hsF[m/8][f][m%8] = bf16(h[m][f]*isq[m]) ----
__global__ __launch_bounds__(256) void k_prep(const float* __restrict__ h,
                                              const float* __restrict__ d,
                                              float* __restrict__ isq,
                                              unsigned short* __restrict__ hsF) {
    __shared__ float tile[32][129];
    __shared__ float iv[32];
    int r0 = blockIdx.x * 32;
    int bb = r0 >> 11;
    int m0 = r0 & (NQ - 1);
    int tid = threadIdx.x;
    if (tid < 32) {
        float v = 1.0f / sqrtf(d[r0 + tid]);
        iv[tid] = v;
        isq[r0 + tid] = v;
    }
    #pragma unroll
    for (int it = 0; it < 16; ++it) {
        int idx = tid + it * 256;
        int mi = idx >> 7, f = idx & 127;
        tile[mi][f] = h[(size_t)(r0 + mi) * FQ + f];
    }
    __syncthreads();
    unsigned short* hb = hsF + (size_t)bb * NQ * FQ;
    #pragma unroll
    for (int it = 0; it < 2; ++it) {
        int p = tid + it * 256;
        int f = p & 127, mc = p >> 7;
        us8 u;
        #pragma unroll
        for (int e = 0; e < 8; ++e)
            u[e] = f2bf(tile[mc * 8 + e][f] * iv[mc * 8 + e]);
        *(us8*)(hb + (size_t)((m0 >> 3) + mc) * 1024 + f * 8) = u;
    }
}

// ---- Kernel 4 (fused): h_out[j][f] = isq[j] * sum_m thr(S[j][m]) * hsF[m][f]
//      8 waves = 2 jg (16 J-rows each) x 4 kh (K=512 each); grid 512 -> 4 waves/SIMD.
//      Pa DOUBLE-BUFFERED (r9 race fix: read(s) vs writes(s+1) never share bytes);
//      QK(s+1) software-pipelined between pa-read(s) and PV(s). ----
__global__ __launch_bounds__(512) void k_fprop(const unsigned short* __restrict__ xnF,
                                               const unsigned short* __restrict__ hsF,
                                               const float* __restrict__ isq,
                                               float* __restrict__ hout, float t) {
    __shared__ unsigned short Pa[2][8][512];    // 2 buffers x 8 waves x 1 KB
    __shared__ float red[2][2][16][128];        // [jg][kh-pair][row][f], 32 KB

    int bid = blockIdx.x;
    int lb = (bid & 7) * 64 + (bid >> 3);       // XCD swizzle: batch-per-XCD
    int bb = lb >> 6;
    int blkJ = lb & 63;
    int row_base = blkJ * 32;
    int wid = threadIdx.x >> 6, lane = threadIdx.x & 63;
    int g = lane >> 4, c = lane & 15;
    int jg = wid >> 2, kh = wid & 3;

    const unsigned short* xb = xnF + (size_t)bb * NQ * FQ;
    const unsigned short* hb = hsF + (size_t)bb * NQ * FQ;

    short8 bJ[4];
    #pragma unroll
    for (int ks = 0; ks < 4; ++ks)
        bJ[ks] = *(const short8*)(xb + (size_t)(blkJ * 2 + jg) * 2048 + (ks * 4 + g) * 128 + c * 8);

    f32x4 acc[8];
    #pragma unroll
    for (int i = 0; i < 8; ++i) acc[i] = (f32x4){0.f, 0.f, 0.f, 0.f};

    int key = (c & 7) << 4;                     // XOR swizzle key (bits 4-6)
    int rbB = (c * 64 + g * 16) ^ key;          // read byte (16B aligned)

    // QK for PV-step s into buffer bf: 2 sub-tiles fill P[j=c][m=0..31]
    #define QKWRITE(s, bf)                                                          \
        {                                                                           \
            char* paw_ = (char*)&Pa[bf][wid][0];                                    \
            _Pragma("unroll")                                                       \
            for (int sub = 0; sub < 2; ++sub) {                                     \
                int I16 = kh * 32 + (s) * 2 + sub;                                  \
                f32x4 p = (f32x4){0.f, 0.f, 0.f, 0.f};                              \
                _Pragma("unroll")                                                   \
                for (int ks = 0; ks < 4; ++ks) {                                    \
                    short8 a_ = *(const short8*)(xb + (size_t)I16 * 2048            \
                                                    + (ks * 4 + g) * 128 + c * 8);  \
                    p = __builtin_amdgcn_mfma_f32_16x16x32_bf16(a_, bJ[ks], p, 0, 0, 0); \
                }                                                                   \
                float x0 = (p[0] > t) ? p[0] : 0.0f;                                \
                float x1 = (p[1] > t) ? p[1] : 0.0f;                                \
                float x2 = (p[2] > t) ? p[2] : 0.0f;                                \
                float x3 = (p[3] > t) ? p[3] : 0.0f;                                \
                u32x2 u;                                                            \
                u[0] = cvtpk(x0, x1);                                               \
                u[1] = cvtpk(x2, x3);                                               \
                int wb = (c * 64 + sub * 32 + g * 8) ^ key;                         \
                *(u32x2*)(paw_ + wb) = u;                                           \
            }                                                                       \
        }

    QKWRITE(0, 0);
    for (int s = 0; s < 16; ++s) {
        asm volatile("s_waitcnt lgkmcnt(0)" ::: "memory");   // buf[s&1] writes done
        __builtin_amdgcn_sched_barrier(0);
        short8 pa = *(const short8*)((char*)&Pa[s & 1][wid][0] + rbB);
        if (s < 15) QKWRITE(s + 1, (s + 1) & 1);             // overlaps pa latency
        #pragma unroll
        for (int ft = 0; ft < 8; ++ft) {
            short8 bfr = *(const short8*)(hb + (size_t)(kh * 64 + s * 4 + g) * 1024
                                             + ft * 128 + c * 8);
            acc[ft] = __builtin_amdgcn_mfma_f32_16x16x32_bf16(pa, bfr, acc[ft], 0, 0, 0);
        }
    }
    #undef QKWRITE

    // two-stage K reduction: kh 0,1 write; kh 2,3 add after barrier
    if (kh < 2) {
        #pragma unroll
        for (int ft = 0; ft < 8; ++ft)
            #pragma unroll
            for (int r = 0; r < 4; ++r)
                red[jg][kh][g * 4 + r][ft * 16 + c] = acc[ft][r];
    }
    __syncthreads();
    if (kh >= 2) {
        #pragma unroll
        for (int ft = 0; ft < 8; ++ft)
            #pragma unroll
            for (int r = 0; r < 4; ++r)
                red[jg][kh - 2][g * 4 + r][ft * 16 + c] += acc[ft][r];
    }
    __syncthreads();

    float* hO = hout + (size_t)bb * NQ * FQ + (size_t)row_base * FQ;
    const float* iq = isq + (size_t)bb * NQ + row_base;
    int tid = threadIdx.x;
    #pragma unroll
    for (int it = 0; it < 8; ++it) {
        int idx = tid + it * 512;
        int row = idx >> 7, f = idx & 127;      // row 0..31
        int j2 = row >> 4, r16 = row & 15;
        float s = iq[row];
        hO[(size_t)row * FQ + f] = red[j2][0][r16][f] * s + red[j2][1][r16][f] * s;
    }
}

// ---- Kernel 5: out = (h3 + x) @ W ----
__global__ __launch_bounds__(256) void k_out(const float* __restrict__ h3,
                                             const float* __restrict__ x,
                                             const float* __restrict__ W,
                                             float* __restrict__ out) {
    __shared__ float hx[8][128];
    int r0 = blockIdx.x * 8;
    int tid = threadIdx.x;
    #pragma unroll
    for (int it = 0; it < 4; ++it) {
        int idx = tid + it * 256;
        int ri = idx >> 7, f = idx & 127;
        size_t gi = (size_t)(r0 + ri) * FQ + f;
        hx[ri][f] = h3[gi] + x[gi];
    }
    __syncthreads();
    int o = tid & 127, half = tid >> 7;
    float acc[4] = {0.f, 0.f, 0.f, 0.f};
    for (int f = 0; f < 128; ++f) {
        float wv = W[f * 128 + o];
        #pragma unroll
        for (int j = 0; j < 4; ++j)
            acc[j] += hx[half * 4 + j][f] * wv;
    }
    #pragma unroll
    for (int j = 0; j < 4; ++j)
        out[(size_t)(r0 + half * 4 + j) * FQ + o] = acc[j];
}

extern "C" void kernel_launch(void* const* d_in, const int* in_sizes, int n_in,
                              void* d_out, int out_size, void* d_ws, size_t ws_size,
                              hipStream_t stream) {
    const float* x = (const float*)d_in[0];
    const float* W = (const float*)d_in[1];
    float* out = (float*)d_out;
    char* ws = (char*)d_ws;

    const size_t CS   = (size_t)BQ * NQ * FQ;             // 2M elems
    const size_t oXN  = 0;
    const size_t oHS  = oXN + CS * 2;                      // 4 MiB
    const size_t oD   = oHS + CS * 2;                      // +4 MiB
    const size_t oISQ = oD  + (size_t)BQ * NQ * 4;         // +64 KiB
    const size_t oHA  = oISQ + (size_t)BQ * NQ * 4;        // +64 KiB
    const size_t oHB  = oHA + CS * 4;                      // +8 MiB
    const size_t need = oHB + CS * 4;                      // ~24 MiB
    if (ws_size < need) return;   // diagnostic: output stays poisoned

    unsigned short* xnF = (unsigned short*)(ws + oXN);
    unsigned short* hsF = (unsigned short*)(ws + oHS);
    float* d   = (float*)(ws + oD);
    float* isq = (float*)(ws + oISQ);
    float* hA  = (float*)(ws + oHA);
    float* hB  = (float*)(ws + oHB);

    const float ts[3] = {0.05f, 0.1f, 0.15f};
    const float* hin = x;
    float* houts[3] = {hA, hB, hA};

    for (int i = 0; i < 3; ++i) {
        k_rownorm<<<BQ * NQ / 16, 256, 0, stream>>>(hin, xnF);
        k_dsum   <<<BQ * 64,      256, 0, stream>>>(xnF, d, ts[i]);
        k_prep   <<<BQ * NQ / 32, 256, 0, stream>>>(hin, d, isq, hsF);
        k_fprop  <<<BQ * 64,      512, 0, stream>>>(xnF, hsF, isq, houts[i], ts[i]);
        hin = houts[i];
    }
    k_out<<<BQ * NQ / 8, 256, 0, stream>>>(hA, x, W, out);
}

// Round 11
// 169.234 us; speedup vs baseline: 1.3181x; 1.3181x over previous
//
#include <hip/hip_runtime.h>
#include <hip/hip_bf16.h>
#include <cstdint>

#define BQ 8
#define NQ 2048
#define FQ 128
#define NG (NQ * 16)            // adjF n-group stride (elems)

typedef __attribute__((ext_vector_type(8))) short short8;
typedef __attribute__((ext_vector_type(4))) float f32x4;
typedef __attribute__((ext_vector_type(4))) unsigned short us4;
typedef __attribute__((ext_vector_type(8))) unsigned short us8;
typedef __attribute__((ext_vector_type(2))) unsigned int u32x2;

__device__ __forceinline__ unsigned short f2bf(float f) {
    union { float f; unsigned int u; } c; c.f = f;
    unsigned int u = c.u;
    u = (u + 0x7FFFu + ((u >> 16) & 1u)) >> 16;   // RNE
    return (unsigned short)u;
}

__device__ __forceinline__ unsigned int cvtpk(float lo, float hi) {
    unsigned int r;
    asm("v_cvt_pk_bf16_f32 %0, %1, %2" : "=v"(r) : "v"(lo), "v"(hi));
    return r;
}

// Fragment layouts (per batch):
//   xnF : [n/16][k/8][n%16][k%8]   addr = (n>>4)*2048 + (k>>3)*128 + (n&15)*8 + (k&7)
//   adjF: [n/16][m/8][n%16][m%8]   addr = (n>>4)*NG   + (m>>3)*128 + (n&15)*8 + (m&7)
//   hsF : [m/8][f][m%8]            addr = (m>>3)*1024 + f*8 + (m&7)

// ---- Kernel 1a: row L2-normalize x -> xnF (16 rows/block) ----
__global__ __launch_bounds__(256) void k_rownorm(const float* __restrict__ h,
                                                 unsigned short* __restrict__ xnF) {
    int t = threadIdx.x;
    int rl = t >> 4, j = t & 15;
    size_t row = (size_t)blockIdx.x * 16 + rl;
    const float* hr = h + row * FQ + j * 8;
    float v[8];
    #pragma unroll
    for (int e = 0; e < 8; ++e) v[e] = hr[e];
    float s = 0.f;
    #pragma unroll
    for (int e = 0; e < 8; ++e) s += v[e] * v[e];
    s += __shfl_xor(s, 1, 64);
    s += __shfl_xor(s, 2, 64);
    s += __shfl_xor(s, 4, 64);
    s += __shfl_xor(s, 8, 64);
    float inv = 1.0f / fmaxf(sqrtf(s), 1e-8f);
    us8 u;
    #pragma unroll
    for (int e = 0; e < 8; ++e) u[e] = f2bf(v[e] * inv);
    *(us8*)(xnF + (size_t)blockIdx.x * 2048 + j * 128 + rl * 8) = u;
}

// ---- Kernel 1b: reduce K-split partials -> h, normalize -> xnF ----
template<int KC>
__global__ __launch_bounds__(256) void k_rownorm4(const float* __restrict__ hp,
                                                  float* __restrict__ hout,
                                                  unsigned short* __restrict__ xnF) {
    const size_t CS = (size_t)BQ * NQ * FQ;
    int t = threadIdx.x;
    int rl = t >> 4, j = t & 15;
    size_t row = (size_t)blockIdx.x * 16 + rl;
    size_t o = row * FQ + j * 8;
    float v[8];
    #pragma unroll
    for (int e = 0; e < 8; ++e) {
        float s = 0.f;
        #pragma unroll
        for (int k = 0; k < KC; ++k) s += hp[k * CS + o + e];
        v[e] = s;
    }
    #pragma unroll
    for (int e = 0; e < 8; ++e) hout[o + e] = v[e];
    float s = 0.f;
    #pragma unroll
    for (int e = 0; e < 8; ++e) s += v[e] * v[e];
    s += __shfl_xor(s, 1, 64);
    s += __shfl_xor(s, 2, 64);
    s += __shfl_xor(s, 4, 64);
    s += __shfl_xor(s, 8, 64);
    float inv = 1.0f / fmaxf(sqrtf(s), 1e-8f);
    us8 u;
    #pragma unroll
    for (int e = 0; e < 8; ++e) u[e] = f2bf(v[e] * inv);
    *(us8*)(xnF + (size_t)blockIdx.x * 2048 + j * 128 + rl * 8) = u;
}

// ---- Kernel 2: S = xn@xn^T, threshold, transposed store to adjF, dpart sums.
//      128x128 tile per 512-thr block; 8 waves = 4 row-quarters x 2 col-halves.
//      Wave = 32 rows x 64 cols: a[2][4]+acc[2][4] ~ 110 VGPR -> 4 waves/SIMD. ----
__global__ __launch_bounds__(512) void k_adj(const unsigned short* __restrict__ xnF,
                                             unsigned short* __restrict__ adjF,
                                             float* __restrict__ dpart, float t) {
    int bid = blockIdx.x;
    int blk = (bid & 7) * (int)(gridDim.x >> 3) + (bid >> 3);   // XCD swizzle
    int bb  = blk >> 8;
    int ij  = blk & 255;
    int I   = ij >> 4, J = ij & 15;
    int wid = threadIdx.x >> 6, lane = threadIdx.x & 63;
    int wr = wid >> 1, wc = wid & 1;          // 4 row-quarters x 2 col-halves
    int g = lane >> 4, c = lane & 15;

    const unsigned short* xb = xnF + (size_t)bb * NQ * FQ;
    int rowb = I * 128 + wr * 32;
    int colb = J * 128 + wc * 64;

    short8 a[2][4];
    #pragma unroll
    for (int mi = 0; mi < 2; ++mi)
        #pragma unroll
        for (int ks = 0; ks < 4; ++ks)
            a[mi][ks] = *(const short8*)(xb + (size_t)((rowb >> 4) + mi) * 2048 + (ks * 4 + g) * 128 + c * 8);

    f32x4 acc[2][4];
    #pragma unroll
    for (int mi = 0; mi < 2; ++mi)
        #pragma unroll
        for (int ni = 0; ni < 4; ++ni) acc[mi][ni] = (f32x4){0.f, 0.f, 0.f, 0.f};

    #pragma unroll
    for (int ni = 0; ni < 4; ++ni) {
        short8 b[4];
        #pragma unroll
        for (int ks = 0; ks < 4; ++ks)
            b[ks] = *(const short8*)(xb + (size_t)((colb >> 4) + ni) * 2048 + (ks * 4 + g) * 128 + c * 8);
        #pragma unroll
        for (int mi = 0; mi < 2; ++mi)
            #pragma unroll
            for (int ks = 0; ks < 4; ++ks)
                acc[mi][ni] = __builtin_amdgcn_mfma_f32_16x16x32_bf16(a[mi][ks], b[ks], acc[mi][ni], 0, 0, 0);
    }

    unsigned short* adjb = adjF + (size_t)bb * NQ * NQ;
    __shared__ float dsm[2][128];
    float dl[2][4];
    #pragma unroll
    for (int mi = 0; mi < 2; ++mi)
        #pragma unroll
        for (int r = 0; r < 4; ++r) dl[mi][r] = 0.f;

    #pragma unroll
    for (int mi = 0; mi < 2; ++mi)
        #pragma unroll
        for (int ni = 0; ni < 4; ++ni) {
            f32x4 v = acc[mi][ni];
            float x0 = (v[0] > t) ? v[0] : 0.0f;   // strict threshold in f32
            float x1 = (v[1] > t) ? v[1] : 0.0f;
            float x2 = (v[2] > t) ? v[2] : 0.0f;
            float x3 = (v[3] > t) ? v[3] : 0.0f;
            dl[mi][0] += x0; dl[mi][1] += x1; dl[mi][2] += x2; dl[mi][3] += x3;
            u32x2 u;
            u[0] = cvtpk(x0, x1);
            u[1] = cvtpk(x2, x3);
            // symmetric: (row=rowb+mi*16+g*4+r, col=colb+ni*16+c) stored at
            // mirror (n=col, m=row) in fragment layout
            *(u32x2*)(adjb + (size_t)((colb >> 4) + ni) * NG
                           + (size_t)((rowb >> 3) + mi * 2 + (g >> 1)) * 128
                           + c * 8 + (g & 1) * 4) = u;
        }

    #pragma unroll
    for (int mi = 0; mi < 2; ++mi)
        #pragma unroll
        for (int r = 0; r < 4; ++r) {
            float s = dl[mi][r];
            s += __shfl_xor(s, 1, 64);
            s += __shfl_xor(s, 2, 64);
            s += __shfl_xor(s, 4, 64);
            s += __shfl_xor(s, 8, 64);
            dl[mi][r] = s;
        }
    if (c == 0) {
        #pragma unroll
        for (int mi = 0; mi < 2; ++mi)
            #pragma unroll
            for (int r = 0; r < 4; ++r)
                dsm[wc][wr * 32 + mi * 16 + g * 4 + r] = dl[mi][r];
    }
    __syncthreads();
    int tid = threadIdx.x;
    if (tid < 128)
        dpart[((size_t)J * 8 + bb) * NQ + I * 128 + tid] = dsm[0][tid] + dsm[1][tid];
}

// ---- Kernel 3: isq = 1/sqrt(sum dpart); hsF[m/8][f][m%8] = bf16(h[m][f]*isq[m]) ----
__global__ __launch_bounds__(256) void k_prep(const float* __restrict__ h,
                                              const float* __restrict__ dpart,
                                              float* __restrict__ isq,
                                              unsigned short* __restrict__ hsF) {
    __shared__ float tile[32][129];
    __shared__ float iv[32];
    int r0 = blockIdx.x * 32;
    int bb = r0 >> 11;
    int m0 = r0 & (NQ - 1);
    int tid = threadIdx.x;
    if (tid < 32) {
        float s = 0.f;
        #pragma unroll
        for (int j = 0; j < 16; ++j)
            s += dpart[((size_t)j * 8 + bb) * NQ + m0 + tid];
        float v = 1.0f / sqrtf(s);
        iv[tid] = v;
        isq[r0 + tid] = v;
    }
    #pragma unroll
    for (int it = 0; it < 16; ++it) {
        int idx = tid + it * 256;
        int mi = idx >> 7, f = idx & 127;
        tile[mi][f] = h[(size_t)(r0 + mi) * FQ + f];
    }
    __syncthreads();
    unsigned short* hb = hsF + (size_t)bb * NQ * FQ;
    #pragma unroll
    for (int it = 0; it < 2; ++it) {
        int p = tid + it * 256;
        int f = p & 127, mc = p >> 7;          // mc 0..3
        us8 u;
        #pragma unroll
        for (int e = 0; e < 8; ++e)
            u[e] = f2bf(tile[mc * 8 + e][f] * iv[mc * 8 + e]);
        *(us8*)(hb + (size_t)((m0 >> 3) + mc) * 1024 + f * 8) = u;
    }
}

// ---- Kernel 4: hpart[kc] = isq[n] * (adjF[:,Kchunk] @ hsF[Kchunk,:])
//      B-chunk staged in LDS via global_load_lds (64 KB phases, 8 kk each),
//      fat 32-row waves, 128 rows/block. KC=4 -> grid 512 = 2 blocks/CU. ----
template<int KC>
__global__ __launch_bounds__(256) void k_gemm2(const unsigned short* __restrict__ adjF,
                                               const unsigned short* __restrict__ hsF,
                                               const float* __restrict__ isq,
                                               float* __restrict__ hpart) {
    constexpr int KE = NQ / KC;        // K elems per chunk
    constexpr int KS = KE / 32;        // kk steps total
    constexpr int PH = 8;              // kk per LDS phase (8*4*1024 elems = 64 KB)
    const size_t CS = (size_t)BQ * NQ * FQ;
    __shared__ unsigned short Bs[PH * 4 * 1024];

    int bid = blockIdx.x;
    int lb = (bid & 7) * (int)(gridDim.x >> 3) + (bid >> 3);   // XCD swizzle
    int kc = lb % KC;
    int rt = (lb / KC) & 15;
    int bb = lb / (KC * 16);
    int wid = threadIdx.x >> 6, lane = threadIdx.x & 63;
    int g = lane >> 4, c = lane & 15;
    int row0 = rt * 128 + wid * 32;

    const unsigned short* adjr = adjF + (size_t)bb * NQ * NQ + (size_t)(row0 >> 4) * NG
                                      + (size_t)((kc * KE) >> 3) * 128;
    const unsigned short* hb   = hsF + (size_t)bb * NQ * FQ + (size_t)((kc * KE) >> 3) * 1024;

    f32x4 acc[2][8];
    #pragma unroll
    for (int mi = 0; mi < 2; ++mi)
        #pragma unroll
        for (int i = 0; i < 8; ++i) acc[mi][i] = (f32x4){0.f, 0.f, 0.f, 0.f};

    for (int ph = 0; ph < KS / PH; ++ph) {
        __syncthreads();     // previous phase's readers done before overwrite
        {
            const unsigned short* src = hb + (size_t)ph * (PH * 4 * 1024);
            #pragma unroll
            for (int it = 0; it < 16; ++it) {
                __builtin_amdgcn_global_load_lds(
                    (const __attribute__((address_space(1))) void*)(src + (size_t)(it * 256 + threadIdx.x) * 8),
                    (__attribute__((address_space(3))) void*)(Bs + (it * 256 + wid * 64) * 8),
                    16, 0, 0);
            }
        }
        __syncthreads();     // compiler drains vmcnt before barrier
        #pragma unroll
        for (int k2 = 0; k2 < PH; ++k2) {
            int kk = ph * PH + k2;
            short8 a0 = *(const short8*)(adjr + (size_t)(kk * 4 + g) * 128 + c * 8);
            short8 a1 = *(const short8*)(adjr + NG + (size_t)(kk * 4 + g) * 128 + c * 8);
            #pragma unroll
            for (int ct = 0; ct < 8; ++ct) {
                short8 bfr = *(const short8*)(Bs + (k2 * 4 + g) * 1024 + ct * 128 + c * 8);
                acc[0][ct] = __builtin_amdgcn_mfma_f32_16x16x32_bf16(a0, bfr, acc[0][ct], 0, 0, 0);
                acc[1][ct] = __builtin_amdgcn_mfma_f32_16x16x32_bf16(a1, bfr, acc[1][ct], 0, 0, 0);
            }
        }
    }

    float* hp = hpart + (size_t)kc * CS + (size_t)bb * NQ * FQ;
    #pragma unroll
    for (int mi = 0; mi < 2; ++mi) {
        float is[4];
        #pragma unroll
        for (int r = 0; r < 4; ++r) is[r] = isq[(size_t)bb * NQ + row0 + mi * 16 + g * 4 + r];
        #pragma unroll
        for (int ct = 0; ct < 8; ++ct)
            #pragma unroll
            for (int r = 0; r < 4; ++r)
                hp[(size_t)(row0 + mi * 16 + g * 4 + r) * FQ + ct * 16 + c] = acc[mi][ct][r] * is[r];
    }
}

// ---- Kernel 5: out = (sum_kc hpart + x) @ W ----
template<int KC>
__global__ __launch_bounds__(256) void k_out4(const float* __restrict__ hp,
                                              const float* __restrict__ x,
                                              const float* __restrict__ W,
                                              float* __restrict__ out) {
    const size_t CS = (size_t)BQ * NQ * FQ;
    __shared__ float hx[8][128];
    int r0 = blockIdx.x * 8;
    int tid = threadIdx.x;
    #pragma unroll
    for (int it = 0; it < 4; ++it) {
        int idx = tid + it * 256;
        int ri = idx >> 7, f = idx & 127;
        size_t gi = (size_t)(r0 + ri) * FQ + f;
        float s = x[gi];
        #pragma unroll
        for (int k = 0; k < KC; ++k) s += hp[k * CS + gi];
        hx[ri][f] = s;
    }
    __syncthreads();
    int o = tid & 127, half = tid >> 7;
    float acc[4] = {0.f, 0.f, 0.f, 0.f};
    for (int f = 0; f < 128; ++f) {
        float wv = W[f * 128 + o];
        #pragma unroll
        for (int j = 0; j < 4; ++j)
            acc[j] += hx[half * 4 + j][f] * wv;
    }
    #pragma unroll
    for (int j = 0; j < 4; ++j)
        out[(size_t)(r0 + half * 4 + j) * FQ + o] = acc[j];
}

template<int KC>
static void run_all(const float* x, const float* W, float* out,
                    unsigned short* adjF, unsigned short* xnF, unsigned short* hsF,
                    float* dpart, float* isq, float* h, float* hpart,
                    hipStream_t stream) {
    const float ts[3] = {0.05f, 0.1f, 0.15f};
    for (int i = 0; i < 3; ++i) {
        if (i == 0) k_rownorm<<<BQ * NQ / 16, 256, 0, stream>>>(x, xnF);
        else        k_rownorm4<KC><<<BQ * NQ / 16, 256, 0, stream>>>(hpart, h, xnF);
        k_adj<<<BQ * 256, 512, 0, stream>>>(xnF, adjF, dpart, ts[i]);
        k_prep<<<BQ * NQ / 32, 256, 0, stream>>>(i == 0 ? x : h, dpart, isq, hsF);
        k_gemm2<KC><<<BQ * 16 * KC, 256, 0, stream>>>(adjF, hsF, isq, hpart);
    }
    k_out4<KC><<<BQ * NQ / 8, 256, 0, stream>>>(hpart, x, W, out);
}

extern "C" void kernel_launch(void* const* d_in, const int* in_sizes, int n_in,
                              void* d_out, int out_size, void* d_ws, size_t ws_size,
                              hipStream_t stream) {
    const float* x = (const float*)d_in[0];
    const float* W = (const float*)d_in[1];
    float* out = (float*)d_out;
    char* ws = (char*)d_ws;

    const size_t CS   = (size_t)BQ * NQ * FQ;
    const size_t oADJ = 0;
    const size_t oXN  = oADJ + (size_t)BQ * NQ * NQ * 2;      // 64 MiB
    const size_t oHST = oXN  + CS * 2;                        // +4 MiB
    const size_t oD   = oHST + CS * 2;                        // +4 MiB
    const size_t oISQ = oD   + (size_t)16 * BQ * NQ * 4;      // +1 MiB
    const size_t oH   = oISQ + (size_t)BQ * NQ * 4;           // +64 KiB
    const size_t oHP  = oH   + CS * 4;                        // +8 MiB
    const size_t need1 = oHP + 1 * CS * 4;
    const size_t need2 = oHP + 2 * CS * 4;
    const size_t need4 = oHP + 4 * CS * 4;

    unsigned short* adjF = (unsigned short*)(ws + oADJ);
    unsigned short* xnF  = (unsigned short*)(ws + oXN);
    unsigned short* hsF  = (unsigned short*)(ws + oHST);
    float* dpart = (float*)(ws + oD);
    float* isq   = (float*)(ws + oISQ);
    float* h     = (float*)(ws + oH);
    float* hpart = (float*)(ws + oHP);

    if (ws_size >= need4)
        run_all<4>(x, W, out, adjF, xnF, hsF, dpart, isq, h, hpart, stream);
    else if (ws_size >= need2)
        run_all<2>(x, W, out, adjF, xnF, hsF, dpart, isq, h, hpart, stream);
    else if (ws_size >= need1)
        run_all<1>(x, W, out, adjF, xnF, hsF, dpart, isq, h, hpart, stream);
    // else: workspace too small (diagnostic — output stays poisoned)
}

// Round 12
// 157.900 us; speedup vs baseline: 1.4127x; 1.0718x over previous
//
#include <hip/hip_runtime.h>
#include <hip/hip_bf16.h>
#include <cstdint>

#define BQ 8
#define NQ 2048
#define FQ 128
#define NG (NQ * 16)            // adjF n-group stride (elems)

typedef __attribute__((ext_vector_type(8))) short short8;
typedef __attribute__((ext_vector_type(4))) float f32x4;
typedef __attribute__((ext_vector_type(8))) unsigned short us8;
typedef __attribute__((ext_vector_type(2))) unsigned int u32x2;

__device__ __forceinline__ unsigned short f2bf(float f) {
    union { float f; unsigned int u; } c; c.f = f;
    unsigned int u = c.u;
    u = (u + 0x7FFFu + ((u >> 16) & 1u)) >> 16;   // RNE
    return (unsigned short)u;
}
__device__ __forceinline__ float bf2f(unsigned short u) {
    union { unsigned int i; float f; } c; c.i = (unsigned int)u << 16; return c.f;
}
__device__ __forceinline__ unsigned int cvtpk(float lo, float hi) {
    unsigned int r;
    asm("v_cvt_pk_bf16_f32 %0, %1, %2" : "=v"(r) : "v"(lo), "v"(hi));
    return r;
}

// Fragment layouts (per batch):
//   xnF : [n/16][k/8][n%16][k%8]   addr = (n>>4)*2048 + (k>>3)*128 + (n&15)*8 + (k&7)
//   adjF: [n/16][m/8][n%16][m%8]   addr = (n>>4)*NG   + (m>>3)*128 + (n&15)*8 + (m&7)
//   hsF : [m/8][f][m%8]            addr = (m>>3)*1024 + f*8 + (m&7)
// hpart, h are bf16 row-major [n][f] (r12 traffic diet).

// ---- Kernel 1a: row L2-normalize x -> xnF (16 rows/block) ----
__global__ __launch_bounds__(256) void k_rownorm(const float* __restrict__ h,
                                                 unsigned short* __restrict__ xnF) {
    int t = threadIdx.x;
    int rl = t >> 4, j = t & 15;
    size_t row = (size_t)blockIdx.x * 16 + rl;
    const float* hr = h + row * FQ + j * 8;
    float v[8];
    #pragma unroll
    for (int e = 0; e < 8; ++e) v[e] = hr[e];
    float s = 0.f;
    #pragma unroll
    for (int e = 0; e < 8; ++e) s += v[e] * v[e];
    s += __shfl_xor(s, 1, 64);
    s += __shfl_xor(s, 2, 64);
    s += __shfl_xor(s, 4, 64);
    s += __shfl_xor(s, 8, 64);
    float inv = 1.0f / fmaxf(sqrtf(s), 1e-8f);
    us8 u;
    #pragma unroll
    for (int e = 0; e < 8; ++e) u[e] = f2bf(v[e] * inv);
    *(us8*)(xnF + (size_t)blockIdx.x * 2048 + j * 128 + rl * 8) = u;
}

// ---- Kernel 1b: reduce bf16 K-split partials -> bf16 h, normalize -> xnF ----
template<int KC>
__global__ __launch_bounds__(256) void k_rownorm4(const unsigned short* __restrict__ hp,
                                                  unsigned short* __restrict__ hout,
                                                  unsigned short* __restrict__ xnF) {
    const size_t CS = (size_t)BQ * NQ * FQ;
    int t = threadIdx.x;
    int rl = t >> 4, j = t & 15;
    size_t row = (size_t)blockIdx.x * 16 + rl;
    size_t o = row * FQ + j * 8;
    float v[8] = {0.f, 0.f, 0.f, 0.f, 0.f, 0.f, 0.f, 0.f};
    #pragma unroll
    for (int k = 0; k < KC; ++k) {
        us8 pv = *(const us8*)(hp + k * CS + o);
        #pragma unroll
        for (int e = 0; e < 8; ++e) v[e] += bf2f(pv[e]);
    }
    us8 hw;
    #pragma unroll
    for (int e = 0; e < 8; ++e) hw[e] = f2bf(v[e]);
    *(us8*)(hout + o) = hw;
    float s = 0.f;
    #pragma unroll
    for (int e = 0; e < 8; ++e) s += v[e] * v[e];
    s += __shfl_xor(s, 1, 64);
    s += __shfl_xor(s, 2, 64);
    s += __shfl_xor(s, 4, 64);
    s += __shfl_xor(s, 8, 64);
    float inv = 1.0f / fmaxf(sqrtf(s), 1e-8f);
    us8 u;
    #pragma unroll
    for (int e = 0; e < 8; ++e) u[e] = f2bf(v[e] * inv);
    *(us8*)(xnF + (size_t)blockIdx.x * 2048 + j * 128 + rl * 8) = u;
}

// ---- Kernel 2 (r11 form): S = xn@xn^T, threshold, transposed store to adjF,
//      dpart sums. 128x128 tile per 512-thr block. ----
__global__ __launch_bounds__(512) void k_adj(const unsigned short* __restrict__ xnF,
                                             unsigned short* __restrict__ adjF,
                                             float* __restrict__ dpart, float t) {
    int bid = blockIdx.x;
    int blk = (bid & 7) * (int)(gridDim.x >> 3) + (bid >> 3);   // XCD swizzle
    int bb  = blk >> 8;
    int ij  = blk & 255;
    int I   = ij >> 4, J = ij & 15;
    int wid = threadIdx.x >> 6, lane = threadIdx.x & 63;
    int wr = wid >> 1, wc = wid & 1;
    int g = lane >> 4, c = lane & 15;

    const unsigned short* xb = xnF + (size_t)bb * NQ * FQ;
    int rowb = I * 128 + wr * 32;
    int colb = J * 128 + wc * 64;

    short8 a[2][4];
    #pragma unroll
    for (int mi = 0; mi < 2; ++mi)
        #pragma unroll
        for (int ks = 0; ks < 4; ++ks)
            a[mi][ks] = *(const short8*)(xb + (size_t)((rowb >> 4) + mi) * 2048 + (ks * 4 + g) * 128 + c * 8);

    f32x4 acc[2][4];
    #pragma unroll
    for (int mi = 0; mi < 2; ++mi)
        #pragma unroll
        for (int ni = 0; ni < 4; ++ni) acc[mi][ni] = (f32x4){0.f, 0.f, 0.f, 0.f};

    #pragma unroll
    for (int ni = 0; ni < 4; ++ni) {
        short8 b[4];
        #pragma unroll
        for (int ks = 0; ks < 4; ++ks)
            b[ks] = *(const short8*)(xb + (size_t)((colb >> 4) + ni) * 2048 + (ks * 4 + g) * 128 + c * 8);
        #pragma unroll
        for (int mi = 0; mi < 2; ++mi)
            #pragma unroll
            for (int ks = 0; ks < 4; ++ks)
                acc[mi][ni] = __builtin_amdgcn_mfma_f32_16x16x32_bf16(a[mi][ks], b[ks], acc[mi][ni], 0, 0, 0);
    }

    unsigned short* adjb = adjF + (size_t)bb * NQ * NQ;
    __shared__ float dsm[2][128];
    float dl[2][4];
    #pragma unroll
    for (int mi = 0; mi < 2; ++mi)
        #pragma unroll
        for (int r = 0; r < 4; ++r) dl[mi][r] = 0.f;

    #pragma unroll
    for (int mi = 0; mi < 2; ++mi)
        #pragma unroll
        for (int ni = 0; ni < 4; ++ni) {
            f32x4 v = acc[mi][ni];
            float x0 = (v[0] > t) ? v[0] : 0.0f;   // strict threshold in f32
            float x1 = (v[1] > t) ? v[1] : 0.0f;
            float x2 = (v[2] > t) ? v[2] : 0.0f;
            float x3 = (v[3] > t) ? v[3] : 0.0f;
            dl[mi][0] += x0; dl[mi][1] += x1; dl[mi][2] += x2; dl[mi][3] += x3;
            u32x2 u;
            u[0] = cvtpk(x0, x1);
            u[1] = cvtpk(x2, x3);
            *(u32x2*)(adjb + (size_t)((colb >> 4) + ni) * NG
                           + (size_t)((rowb >> 3) + mi * 2 + (g >> 1)) * 128
                           + c * 8 + (g & 1) * 4) = u;
        }

    #pragma unroll
    for (int mi = 0; mi < 2; ++mi)
        #pragma unroll
        for (int r = 0; r < 4; ++r) {
            float s = dl[mi][r];
            s += __shfl_xor(s, 1, 64);
            s += __shfl_xor(s, 2, 64);
            s += __shfl_xor(s, 4, 64);
            s += __shfl_xor(s, 8, 64);
            dl[mi][r] = s;
        }
    if (c == 0) {
        #pragma unroll
        for (int mi = 0; mi < 2; ++mi)
            #pragma unroll
            for (int r = 0; r < 4; ++r)
                dsm[wc][wr * 32 + mi * 16 + g * 4 + r] = dl[mi][r];
    }
    __syncthreads();
    int tid = threadIdx.x;
    if (tid < 128)
        dpart[((size_t)J * 8 + bb) * NQ + I * 128 + tid] = dsm[0][tid] + dsm[1][tid];
}

// ---- Kernel 3a (iter 0): isq from dpart; hsF from f32 x ----
__global__ __launch_bounds__(256) void k_prep_f32(const float* __restrict__ h,
                                                  const float* __restrict__ dpart,
                                                  float* __restrict__ isq,
                                                  unsigned short* __restrict__ hsF) {
    __shared__ float tile[32][129];
    __shared__ float iv[32];
    int r0 = blockIdx.x * 32;
    int bb = r0 >> 11;
    int m0 = r0 & (NQ - 1);
    int tid = threadIdx.x;
    if (tid < 32) {
        float s = 0.f;
        #pragma unroll
        for (int j = 0; j < 16; ++j)
            s += dpart[((size_t)j * 8 + bb) * NQ + m0 + tid];
        float v = 1.0f / sqrtf(s);
        iv[tid] = v;
        isq[r0 + tid] = v;
    }
    #pragma unroll
    for (int it = 0; it < 16; ++it) {
        int idx = tid + it * 256;
        int mi = idx >> 7, f = idx & 127;
        tile[mi][f] = h[(size_t)(r0 + mi) * FQ + f];
    }
    __syncthreads();
    unsigned short* hb = hsF + (size_t)bb * NQ * FQ;
    #pragma unroll
    for (int it = 0; it < 2; ++it) {
        int p = tid + it * 256;
        int f = p & 127, mc = p >> 7;
        us8 u;
        #pragma unroll
        for (int e = 0; e < 8; ++e)
            u[e] = f2bf(tile[mc * 8 + e][f] * iv[mc * 8 + e]);
        *(us8*)(hb + (size_t)((m0 >> 3) + mc) * 1024 + f * 8) = u;
    }
}

// ---- Kernel 3b (iters 1,2): isq from dpart; hsF from bf16 h ----
__global__ __launch_bounds__(256) void k_prep_bf16(const unsigned short* __restrict__ h,
                                                   const float* __restrict__ dpart,
                                                   float* __restrict__ isq,
                                                   unsigned short* __restrict__ hsF) {
    __shared__ float tile[32][129];
    __shared__ float iv[32];
    int r0 = blockIdx.x * 32;
    int bb = r0 >> 11;
    int m0 = r0 & (NQ - 1);
    int tid = threadIdx.x;
    if (tid < 32) {
        float s = 0.f;
        #pragma unroll
        for (int j = 0; j < 16; ++j)
            s += dpart[((size_t)j * 8 + bb) * NQ + m0 + tid];
        float v = 1.0f / sqrtf(s);
        iv[tid] = v;
        isq[r0 + tid] = v;
    }
    #pragma unroll
    for (int it = 0; it < 16; ++it) {
        int idx = tid + it * 256;
        int mi = idx >> 7, f = idx & 127;
        tile[mi][f] = bf2f(h[(size_t)(r0 + mi) * FQ + f]);
    }
    __syncthreads();
    unsigned short* hb = hsF + (size_t)bb * NQ * FQ;
    #pragma unroll
    for (int it = 0; it < 2; ++it) {
        int p = tid + it * 256;
        int f = p & 127, mc = p >> 7;
        us8 u;
        #pragma unroll
        for (int e = 0; e < 8; ++e)
            u[e] = f2bf(tile[mc * 8 + e][f] * iv[mc * 8 + e]);
        *(us8*)(hb + (size_t)((m0 >> 3) + mc) * 1024 + f * 8) = u;
    }
}

// ---- Kernel 4: hpart[kc] (bf16) = isq[n] * (adjF[:,Kchunk] @ hsF[Kchunk,:])
//      LDS-staged B via global_load_lds, fat 32-row waves, 128 rows/block. ----
template<int KC>
__global__ __launch_bounds__(256) void k_gemm2(const unsigned short* __restrict__ adjF,
                                               const unsigned short* __restrict__ hsF,
                                               const float* __restrict__ isq,
                                               unsigned short* __restrict__ hpart) {
    constexpr int KE = NQ / KC;
    constexpr int KS = KE / 32;
    constexpr int PH = 8;              // 64 KB LDS phase
    const size_t CS = (size_t)BQ * NQ * FQ;
    __shared__ unsigned short Bs[PH * 4 * 1024];

    int bid = blockIdx.x;
    int lb = (bid & 7) * (int)(gridDim.x >> 3) + (bid >> 3);   // XCD swizzle
    int kc = lb % KC;
    int rt = (lb / KC) & 15;
    int bb = lb / (KC * 16);
    int wid = threadIdx.x >> 6, lane = threadIdx.x & 63;
    int g = lane >> 4, c = lane & 15;
    int row0 = rt * 128 + wid * 32;

    const unsigned short* adjr = adjF + (size_t)bb * NQ * NQ + (size_t)(row0 >> 4) * NG
                                      + (size_t)((kc * KE) >> 3) * 128;
    const unsigned short* hb   = hsF + (size_t)bb * NQ * FQ + (size_t)((kc * KE) >> 3) * 1024;

    f32x4 acc[2][8];
    #pragma unroll
    for (int mi = 0; mi < 2; ++mi)
        #pragma unroll
        for (int i = 0; i < 8; ++i) acc[mi][i] = (f32x4){0.f, 0.f, 0.f, 0.f};

    for (int ph = 0; ph < KS / PH; ++ph) {
        __syncthreads();
        {
            const unsigned short* src = hb + (size_t)ph * (PH * 4 * 1024);
            #pragma unroll
            for (int it = 0; it < 16; ++it) {
                __builtin_amdgcn_global_load_lds(
                    (const __attribute__((address_space(1))) void*)(src + (size_t)(it * 256 + threadIdx.x) * 8),
                    (__attribute__((address_space(3))) void*)(Bs + (it * 256 + wid * 64) * 8),
                    16, 0, 0);
            }
        }
        __syncthreads();
        #pragma unroll
        for (int k2 = 0; k2 < PH; ++k2) {
            int kk = ph * PH + k2;
            short8 a0 = *(const short8*)(adjr + (size_t)(kk * 4 + g) * 128 + c * 8);
            short8 a1 = *(const short8*)(adjr + NG + (size_t)(kk * 4 + g) * 128 + c * 8);
            #pragma unroll
            for (int ct = 0; ct < 8; ++ct) {
                short8 bfr = *(const short8*)(Bs + (k2 * 4 + g) * 1024 + ct * 128 + c * 8);
                acc[0][ct] = __builtin_amdgcn_mfma_f32_16x16x32_bf16(a0, bfr, acc[0][ct], 0, 0, 0);
                acc[1][ct] = __builtin_amdgcn_mfma_f32_16x16x32_bf16(a1, bfr, acc[1][ct], 0, 0, 0);
            }
        }
    }

    unsigned short* hp = hpart + (size_t)kc * CS + (size_t)bb * NQ * FQ;
    #pragma unroll
    for (int mi = 0; mi < 2; ++mi) {
        float is[4];
        #pragma unroll
        for (int r = 0; r < 4; ++r) is[r] = isq[(size_t)bb * NQ + row0 + mi * 16 + g * 4 + r];
        #pragma unroll
        for (int ct = 0; ct < 8; ++ct)
            #pragma unroll
            for (int r = 0; r < 4; ++r)
                hp[(size_t)(row0 + mi * 16 + g * 4 + r) * FQ + ct * 16 + c] = f2bf(acc[mi][ct][r] * is[r]);
    }
}

// ---- Kernel 5: out = (sum_kc hpart(bf16) + x) @ W ----
template<int KC>
__global__ __launch_bounds__(256) void k_out4(const unsigned short* __restrict__ hp,
                                              const float* __restrict__ x,
                                              const float* __restrict__ W,
                                              float* __restrict__ out) {
    const size_t CS = (size_t)BQ * NQ * FQ;
    __shared__ float hx[8][128];
    int r0 = blockIdx.x * 8;
    int tid = threadIdx.x;
    #pragma unroll
    for (int it = 0; it < 4; ++it) {
        int idx = tid + it * 256;
        int ri = idx >> 7, f = idx & 127;
        size_t gi = (size_t)(r0 + ri) * FQ + f;
        float s = x[gi];
        #pragma unroll
        for (int k = 0; k < KC; ++k) s += bf2f(hp[k * CS + gi]);
        hx[ri][f] = s;
    }
    __syncthreads();
    int o = tid & 127, half = tid >> 7;
    float acc[4] = {0.f, 0.f, 0.f, 0.f};
    for (int f = 0; f < 128; ++f) {
        float wv = W[f * 128 + o];
        #pragma unroll
        for (int j = 0; j < 4; ++j)
            acc[j] += hx[half * 4 + j][f] * wv;
    }
    #pragma unroll
    for (int j = 0; j < 4; ++j)
        out[(size_t)(r0 + half * 4 + j) * FQ + o] = acc[j];
}

template<int KC>
static void run_all(const float* x, const float* W, float* out,
                    unsigned short* adjF, unsigned short* xnF, unsigned short* hsF,
                    float* dpart, float* isq, unsigned short* h, unsigned short* hpart,
                    hipStream_t stream) {
    const float ts[3] = {0.05f, 0.1f, 0.15f};
    for (int i = 0; i < 3; ++i) {
        if (i == 0) k_rownorm<<<BQ * NQ / 16, 256, 0, stream>>>(x, xnF);
        else        k_rownorm4<KC><<<BQ * NQ / 16, 256, 0, stream>>>(hpart, h, xnF);
        k_adj<<<BQ * 256, 512, 0, stream>>>(xnF, adjF, dpart, ts[i]);
        if (i == 0) k_prep_f32 <<<BQ * NQ / 32, 256, 0, stream>>>(x, dpart, isq, hsF);
        else        k_prep_bf16<<<BQ * NQ / 32, 256, 0, stream>>>(h, dpart, isq, hsF);
        k_gemm2<KC><<<BQ * 16 * KC, 256, 0, stream>>>(adjF, hsF, isq, hpart);
    }
    k_out4<KC><<<BQ * NQ / 8, 256, 0, stream>>>(hpart, x, W, out);
}

extern "C" void kernel_launch(void* const* d_in, const int* in_sizes, int n_in,
                              void* d_out, int out_size, void* d_ws, size_t ws_size,
                              hipStream_t stream) {
    const float* x = (const float*)d_in[0];
    const float* W = (const float*)d_in[1];
    float* out = (float*)d_out;
    char* ws = (char*)d_ws;

    const size_t CS   = (size_t)BQ * NQ * FQ;
    const size_t oADJ = 0;
    const size_t oXN  = oADJ + (size_t)BQ * NQ * NQ * 2;      // 64 MiB
    const size_t oHST = oXN  + CS * 2;                        // +4 MiB
    const size_t oD   = oHST + CS * 2;                        // +4 MiB
    const size_t oISQ = oD   + (size_t)16 * BQ * NQ * 4;      // +1 MiB
    const size_t oH   = oISQ + (size_t)BQ * NQ * 4;           // +64 KiB
    const size_t oHP  = oH   + CS * 2;                        // +4 MiB (bf16 h)
    const size_t need1 = oHP + 1 * CS * 2;                    // bf16 partials
    const size_t need2 = oHP + 2 * CS * 2;
    const size_t need4 = oHP + 4 * CS * 2;

    unsigned short* adjF = (unsigned short*)(ws + oADJ);
    unsigned short* xnF  = (unsigned short*)(ws + oXN);
    unsigned short* hsF  = (unsigned short*)(ws + oHST);
    float* dpart = (float*)(ws + oD);
    float* isq   = (float*)(ws + oISQ);
    unsigned short* h     = (unsigned short*)(ws + oH);
    unsigned short* hpart = (unsigned short*)(ws + oHP);

    if (ws_size >= need4)
        run_all<4>(x, W, out, adjF, xnF, hsF, dpart, isq, h, hpart, stream);
    else if (ws_size >= need2)
        run_all<2>(x, W, out, adjF, xnF, hsF, dpart, isq, h, hpart, stream);
    else if (ws_size >= need1)
        run_all<1>(x, W, out, adjF, xnF, hsF, dpart, isq, h, hpart, stream);
    // else: workspace too small (diagnostic — output stays poisoned)
}